// Round 2
// baseline (214.145 us; speedup 1.0000x reference)
//
#include <hip/hip_runtime.h>
#include <math.h>

// NeRF ray integration, v2: 2 rays per 64-lane wave (32-lane segments),
// 4 samples per lane, all streams as float4 (16 B/lane).
// wi[s] = exp(-excl_cumsum(sigma*dt)[s]) - exp(-incl_cumsum(sigma*dt)[s])
// dt[s] = t[s+1]-t[s], dt[S-1] = 0 (infinite=False). Output t == input t
// (input is pre-sorted; reference's sort is a no-op).

#define NRAYS 65536
#define S 128
#define RAYS_PER_BLOCK 8   // 4 waves * 2 rays

typedef float __attribute__((ext_vector_type(4))) fvec4;

__global__ __launch_bounds__(256) void nerf_render_kernel(
    const float* __restrict__ t,
    const float* __restrict__ sigma,
    const float* __restrict__ color,
    float* __restrict__ out_color,   // [N,3]
    float* __restrict__ out_depth,   // [N,1]
    float* __restrict__ out_wi,      // [N,S]
    float* __restrict__ out_t)       // [N,S]
{
    const int lane    = threadIdx.x & 63;
    const int seglane = lane & 31;                      // lane within 32-lane segment
    const int wave    = threadIdx.x >> 6;
    // ray = 2 rays per wave; segment 0 -> even, segment 1 -> odd
    const int ray = blockIdx.x * RAYS_PER_BLOCK + wave * 2 + (lane >> 5);

    const long sbase = (long)ray * S + 4 * seglane;     // first of 4 samples

    // --- loads: 16 B/lane, fully coalesced across the wave ---
    const fvec4 tv = *(const fvec4*)(t + sbase);
    const fvec4 sv = *(const fvec4*)(sigma + sbase);
    const fvec4* cp = (const fvec4*)(color + (long)ray * (S * 3) + 12 * seglane);
    const fvec4 c0 = cp[0];   // r0 g0 b0 r1
    const fvec4 c1 = cp[1];   // g1 b1 r2 g2
    const fvec4 c2 = cp[2];   // b2 r3 g3 b3

    // --- dt stencil: next lane's t.x closes the last interval ---
    const float t_next = __shfl_down(tv.x, 1, 32);      // t[4*seglane+4]
    const float dt0 = tv.y - tv.x;
    const float dt1 = tv.z - tv.y;
    const float dt2 = tv.w - tv.z;
    const float dt3 = (seglane == 31) ? 0.0f : (t_next - tv.w);

    const float p0  = sv.x * dt0;                       // local inclusive prefix
    const float p1  = p0 + sv.y * dt1;
    const float p2  = p1 + sv.z * dt2;
    const float tot = p2 + sv.w * dt3;

    // --- segment-inclusive scan of per-lane totals (5 shfl_up steps) ---
    float scan = tot;
    #pragma unroll
    for (int off = 1; off < 32; off <<= 1) {
        const float v = __shfl_up(scan, off, 32);
        if (seglane >= off) scan += v;
    }
    const float excl = scan - tot;                      // cumsum before sample 4*seglane

    const float E0 = expf(-excl);
    const float e0 = expf(-(excl + p0));
    const float e1 = expf(-(excl + p1));
    const float e2 = expf(-(excl + p2));
    const float e3 = expf(-scan);
    const float wi0 = E0 - e0;
    const float wi1 = e0 - e1;
    const float wi2 = e1 - e2;
    const float wi3 = e2 - e3;

    // --- streamed outputs (nontemporal: no reuse, keep inputs cached) ---
    fvec4 wiv; wiv.x = wi0; wiv.y = wi1; wiv.z = wi2; wiv.w = wi3;
    __builtin_nontemporal_store(wiv, (fvec4*)(out_wi + sbase));
    __builtin_nontemporal_store(tv,  (fvec4*)(out_t + sbase));

    // --- per-ray reductions: rgb + depth (width-32 butterfly) ---
    float r = wi0 * c0.x + wi1 * c0.w + wi2 * c1.z + wi3 * c2.y;
    float g = wi0 * c0.y + wi1 * c1.x + wi2 * c1.w + wi3 * c2.z;
    float b = wi0 * c0.z + wi1 * c1.y + wi2 * c2.x + wi3 * c2.w;
    float d = wi0 * tv.x + wi1 * tv.y + wi2 * tv.z + wi3 * tv.w;

    #pragma unroll
    for (int off = 16; off >= 1; off >>= 1) {
        r += __shfl_xor(r, off, 32);
        g += __shfl_xor(g, off, 32);
        b += __shfl_xor(b, off, 32);
        d += __shfl_xor(d, off, 32);
    }

    if (seglane == 0) {
        out_color[(long)ray * 3 + 0] = r;
        out_color[(long)ray * 3 + 1] = g;
        out_color[(long)ray * 3 + 2] = b;
        out_depth[ray] = d;
    }
}

extern "C" void kernel_launch(void* const* d_in, const int* in_sizes, int n_in,
                              void* d_out, int out_size, void* d_ws, size_t ws_size,
                              hipStream_t stream) {
    const float* t     = (const float*)d_in[0];
    const float* sigma = (const float*)d_in[1];
    const float* color = (const float*)d_in[2];

    float* out = (float*)d_out;
    float* out_color = out;                         // N*3
    float* out_depth = out_color + (long)NRAYS * 3; // N
    float* out_wi    = out_depth + NRAYS;           // N*S
    float* out_t     = out_wi + (long)NRAYS * S;    // N*S

    const int blocks = NRAYS / RAYS_PER_BLOCK;      // 8192
    nerf_render_kernel<<<blocks, 256, 0, stream>>>(
        t, sigma, color, out_color, out_depth, out_wi, out_t);
}